// Round 10
// baseline (111.246 us; speedup 1.0000x reference)
//
#include <hip/hip_runtime.h>

// CCQC classifier, GEMM formulation. R10: 8-wave build (occupancy fix).
//   1. qprep (blocks 0..1023): build rows of U via REVERSED ADJOINT circuit.
//      512-thread block per basis state; j = (wv<<7)|(k<<6)|lane, 2 f32x2
//      regs/lane. 4 blocks/CU x 8 waves = 32 waves/CU (100% cap).
//      101-gate pre-adjointed program computed into LDS at block start.
//      Cross-wave gates (j-bits 7..9) via double-buffered LDS exchange,
//      1 barrier each. Wt interleaved: row 2j=Re, 2j+1=Im.
//      qprep (blocks 1024..3071): xconv X fp32 -> fp16 (overlaps build).
//   2. gemm_z: C = Xh * Wt^T, M=8192 N=2048 K=832, 128x128 tile, BK=64,
//      double-buffered global_load_lds, XOR bank-swizzle (both-sides),
//      fused |psi|^2 epilogue -> 32 sign-uniform chunk partials.
//   3. nll_mean: logits from chunk partials, log-softmax NLL, mean.

namespace {

typedef float f32x2 __attribute__((ext_vector_type(2)));
typedef _Float16 f16x8 __attribute__((ext_vector_type(8)));
typedef float f32x4v __attribute__((ext_vector_type(4)));

__device__ __forceinline__ f32x2 swap2(f32x2 v) {
  return __builtin_shufflevector(v, v, 1, 0);
}
__device__ __forceinline__ f32x2 shfl_xor2(f32x2 v, int lm) {
  f32x2 r;
  r.x = __shfl_xor(v.x, lm, 64);
  r.y = __shfl_xor(v.y, lm, 64);
  return r;
}
__device__ __forceinline__ f32x2 sel2(bool c, f32x2 a, f32x2 b) {
  f32x2 r; r.x = c ? a.x : b.x; r.y = c ? a.y : b.y; return r;
}

struct c2 { float r, i; };
struct m2c { c2 a00, a01, a10, a11; };

__device__ __forceinline__ c2 cmul(c2 x, c2 y) { return {x.r*y.r - x.i*y.i, x.r*y.i + x.i*y.r}; }
__device__ __forceinline__ c2 cadd(c2 x, c2 y) { return {x.r + y.r, x.i + y.i}; }
__device__ __forceinline__ c2 conjc(c2 a) { return {a.r, -a.i}; }
__device__ __forceinline__ m2c mmul(m2c A, m2c B) {
  m2c C;
  C.a00 = cadd(cmul(A.a00, B.a00), cmul(A.a01, B.a10));
  C.a01 = cadd(cmul(A.a00, B.a01), cmul(A.a01, B.a11));
  C.a10 = cadd(cmul(A.a10, B.a00), cmul(A.a11, B.a10));
  C.a11 = cadd(cmul(A.a10, B.a01), cmul(A.a11, B.a11));
  return C;
}
__device__ __forceinline__ m2c mrx(float t) {
  float c = cosf(0.5f * t), s = sinf(0.5f * t);
  return { {c, 0.f}, {0.f, -s}, {0.f, -s}, {c, 0.f} };
}
__device__ __forceinline__ m2c mrz(float t) {
  float c = cosf(0.5f * t), s = sinf(0.5f * t);
  return { {c, -s}, {0.f, 0.f}, {0.f, 0.f}, {c, s} };
}

struct MatP { f32x2 u00r, u00i, u01r, u01i, u10r, u10i, u11r, u11i; };

__device__ __forceinline__ MatP ldmatL(const float* progL, int slot) {
  const float4* p = reinterpret_cast<const float4*>(progL + slot * 16);
  float4 a = p[0], b = p[1], c = p[2], d = p[3];
  MatP m;
  m.u00r = f32x2{a.x, a.y}; m.u00i = f32x2{a.z, a.w};
  m.u01r = f32x2{b.x, b.y}; m.u01i = f32x2{b.z, b.w};
  m.u10r = f32x2{c.x, c.y}; m.u10i = f32x2{c.z, c.w};
  m.u11r = f32x2{d.x, d.y}; m.u11i = f32x2{d.z, d.w};
  return m;
}

__device__ __forceinline__ f32x2 cmad(f32x2 acc, f32x2 cr2, f32x2 ci2, f32x2 v) {
  return acc + cr2 * v + ci2 * swap2(v);
}
__device__ __forceinline__ f32x2 cmulp(f32x2 cr2, f32x2 ci2, f32x2 v) {
  return cr2 * v + ci2 * swap2(v);
}

// 8-wave/state gate applier. s[2]: k = j-bit 6. wv bits: j-bits 7..9.
// bt: target j-bit; bc: ctrl j-bit or -1. cm=1 => only k=1 amps touched.
__device__ __forceinline__ void apply_gate8(f32x2 (&s)[2], f32x2* lxb,
                                            const int wv, const int lane,
                                            const MatP mIn, const int bt,
                                            const int bc) {
  MatP m = mIn;
  const f32x2 oner{1.f, 1.f}, zero{0.f, 0.f};
  int cm = 0;
  bool fold = false, cl = true;
  if (bc >= 7)      { cl = ((wv >> (bc - 7)) & 1) != 0; fold = true; }
  else if (bc == 6) { cm = 1; }
  else if (bc >= 0) { cl = ((lane >> bc) & 1) != 0; fold = true; }

  if (bt >= 7) {
    // cross-wave exchange (1 barrier; caller alternates lxb)
    const int tb = bt - 7;
    const bool hi = ((wv >> tb) & 1) != 0;
    f32x2 cAr = sel2(hi, m.u11r, m.u00r), cAi = sel2(hi, m.u11i, m.u00i);
    f32x2 cBr = sel2(hi, m.u10r, m.u01r), cBi = sel2(hi, m.u10i, m.u01i);
    if (fold) {
      cAr = sel2(cl, cAr, oner); cAi = sel2(cl, cAi, zero);
      cBr = sel2(cl, cBr, zero); cBi = sel2(cl, cBi, zero);
    }
    lxb[(wv * 2 + 0) * 64 + lane] = s[0];
    lxb[(wv * 2 + 1) * 64 + lane] = s[1];
    __syncthreads();
    const int pw = wv ^ (1 << tb);
    #pragma unroll
    for (int k = 0; k < 2; ++k) {
      if (cm && k == 0) continue;
      const f32x2 pv = lxb[(pw * 2 + k) * 64 + lane];
      s[k] = cmad(cmulp(cAr, cAi, s[k]), cBr, cBi, pv);
    }
  } else if (bt == 6) {
    // in-lane register pair (k0=0, k1=1)
    if (fold) {
      m.u00r = sel2(cl, m.u00r, oner); m.u00i = sel2(cl, m.u00i, zero);
      m.u01r = sel2(cl, m.u01r, zero); m.u01i = sel2(cl, m.u01i, zero);
      m.u10r = sel2(cl, m.u10r, zero); m.u10i = sel2(cl, m.u10i, zero);
      m.u11r = sel2(cl, m.u11r, oner); m.u11i = sel2(cl, m.u11i, zero);
    }
    const f32x2 a = s[0], b = s[1];
    s[0] = cmad(cmulp(m.u00r, m.u00i, a), m.u01r, m.u01i, b);
    s[1] = cmad(cmulp(m.u10r, m.u10i, a), m.u11r, m.u11i, b);
  } else {
    // lane-bit target: shuffle
    const bool hi = ((lane >> bt) & 1) != 0;
    f32x2 cAr = sel2(hi, m.u11r, m.u00r), cAi = sel2(hi, m.u11i, m.u00i);
    f32x2 cBr = sel2(hi, m.u10r, m.u01r), cBi = sel2(hi, m.u10i, m.u01i);
    if (fold) {
      cAr = sel2(cl, cAr, oner); cAi = sel2(cl, cAi, zero);
      cBr = sel2(cl, cBr, zero); cBi = sel2(cl, cBi, zero);
    }
    const int lm = 1 << bt;
    #pragma unroll
    for (int k = 0; k < 2; ++k) {
      if (cm && k == 0) continue;
      const f32x2 p = shfl_xor2(s[k], lm);
      s[k] = cmad(cmulp(cAr, cAi, s[k]), cBr, cBi, p);
    }
  }
}

// Fused prep. Blocks <1024: build row n=blockIdx of U (8 waves, 2 regs/lane).
// Blocks >=1024: xconv. Program slot layout (reversed-adjoint exec order):
//   dd=0 (d=4): slot0 = U0; 1..10 = CU i=9..0; 11..20 = U1 i=9..0.
//   dd>=1: base=21+(dd-1)*20: 0..9 = CU i=9..0; 10..19 = U1 i=9..0.
// U0[d<4] pre-fused into U1[d+1, i=0]. 101 slots.
__global__ __launch_bounds__(512) void qprep(const float* __restrict__ w,
                                             const float* __restrict__ w1,
                                             const float* __restrict__ w2,
                                             const float* __restrict__ x,
                                             _Float16* __restrict__ Wt,
                                             _Float16* __restrict__ Xh) {
  const int tid = threadIdx.x;
  if (blockIdx.x >= 1024) {
    // ---- xconv ----
    const int t = (blockIdx.x - 1024) * 512 + tid;
    const int b = t >> 7;
    const int j = (t & 127) * 8;
    f16x8 o;
    if (j < 784) {
      const float4* p = reinterpret_cast<const float4*>(x + (size_t)b * 784 + j);
      const float4 v0 = p[0], v1 = p[1];
      o[0] = (_Float16)v0.x; o[1] = (_Float16)v0.y;
      o[2] = (_Float16)v0.z; o[3] = (_Float16)v0.w;
      o[4] = (_Float16)v1.x; o[5] = (_Float16)v1.y;
      o[6] = (_Float16)v1.z; o[7] = (_Float16)v1.w;
    } else {
      #pragma unroll
      for (int q = 0; q < 8; ++q) o[q] = (_Float16)0.f;
    }
    *reinterpret_cast<f16x8*>(Xh + (size_t)b * 1024 + j) = o;
    return;
  }

  // ---- build_W ----
  __shared__ float progL[101 * 16];   // 6.3 KB
  __shared__ f32x2 lx[2][1024];       // 2 x 8 KB double-buffered exchange

  if (tid < 105) {
    const int t = tid;
    m2c U{}; int slot = -1;
    if (t < 50) {
      const int d = t / 10, i = t % 10;
      const float* p = w + (d * 10 + i) * 5;
      U = mmul(mrx(p[2]), mmul(mrz(p[1]), mrx(p[0])));
      if (i == 0 && d > 0) {
        m2c U0 = mmul(mrz(w2[d - 1]), mrx(w1[d - 1]));
        U = mmul(U, U0);
      }
      const int dd = 4 - d;
      const int base = (dd == 0) ? 0 : 21 + (dd - 1) * 20;
      slot = base + ((d == 4) ? 11 : 10) + (9 - i);
    } else if (t < 100) {
      const int s = t - 50; const int d = s / 10, i = s % 10;
      const float* p = w + (d * 10 + i) * 5;
      U = mmul(mrx(p[4]), mrz(p[3]));
      const int dd = 4 - d;
      const int base = (dd == 0) ? 0 : 21 + (dd - 1) * 20;
      slot = base + ((d == 4) ? 1 : 0) + (9 - i);
    } else {
      const int d = t - 100;
      if (d == 4) {
        U = mmul(mrz(w2[d]), mrx(w1[d]));
        slot = 0;
      }
    }
    if (slot >= 0) {
      // Adjoint (conj-transpose), packed {re, re, -im, im} per entry.
      const c2 A[4] = {conjc(U.a00), conjc(U.a10), conjc(U.a01), conjc(U.a11)};
      float* o = progL + slot * 16;
      #pragma unroll
      for (int q = 0; q < 4; ++q) {
        o[q*4 + 0] = A[q].r; o[q*4 + 1] = A[q].r;
        o[q*4 + 2] = -A[q].i; o[q*4 + 3] = A[q].i;
      }
    }
  }
  __syncthreads();

  const int lane = tid & 63;
  const int wv = tid >> 6;           // 0..7 = j-bits 7..9
  const int n = blockIdx.x;

  f32x2 s[2];
  #pragma unroll
  for (int k = 0; k < 2; ++k) {
    const int j = (wv << 7) | (k << 6) | lane;
    s[k].x = (j == n) ? 1.f : 0.f;
    s[k].y = 0.f;
  }

  int p = 0, ph = 0;
  #pragma unroll
  for (int dd = 0; dd < 5; ++dd) {
    const int d = 4 - dd;
    if (d == 4) {
      apply_gate8(s, &lx[ph & 1][0], wv, lane, ldmatL(progL, p), 9, -1);
      ++p; ++ph;
    }
    const int r = (d & 1) ? 3 : 1;
    #pragma unroll
    for (int ii = 0; ii < 10; ++ii) {
      const int i = 9 - ii;
      const int c = (i + r) % 10;
      const int bt = 9 - i, bc = 9 - c;
      apply_gate8(s, &lx[ph & 1][0], wv, lane, ldmatL(progL, p), bt, bc);
      ++p; if (bt >= 7) ++ph;
    }
    #pragma unroll
    for (int ii = 0; ii < 10; ++ii) {
      const int i = 9 - ii;
      const int bt = 9 - i;
      apply_gate8(s, &lx[ph & 1][0], wv, lane, ldmatL(progL, p), bt, -1);
      ++p; if (bt >= 7) ++ph;
    }
  }

  // psi = U^dagger e_n => U[n][j] = (s.x, -s.y)
  #pragma unroll
  for (int k = 0; k < 2; ++k) {
    const int j = (wv << 7) | (k << 6) | lane;
    Wt[(size_t)(2 * n) * 1024 + j] = (_Float16)s[k].x;
    Wt[(size_t)(2 * n + 1) * 1024 + j] = (_Float16)(-s[k].y);
  }
}

// ---------------- LDS-staged GEMM ----------------
// Tile 128(M) x 128(N-rows, interleaved re/im = 64 js), BK=64, 13 K-steps
// (K=832 covers the 784 nonzero cols). 4 waves = 2(M) x 2(N), 64x64 each.
// LDS swizzle: row r's 8 16B-slots permuted s -> s^(r&7); staged with linear
// LDS dest + swizzled GLOBAL source; read with same XOR (rule #21).
#define GZ_NSTEP 13

__device__ __forceinline__ void stage_tiles(const _Float16* __restrict__ gA,
                                            const _Float16* __restrict__ gB,
                                            _Float16* sA, _Float16* sB,
                                            int k0, int wv, int lane) {
  const int rIn = lane >> 3;                    // row within chunk (0..7)
  const int colh = ((lane & 7) ^ rIn) * 8;      // swizzled source 16B-slot
  #pragma unroll
  for (int c = 0; c < 4; ++c) {
    const int chunk = wv * 4 + c;
    const size_t grow = (size_t)(chunk * 8 + rIn) * 1024 + k0 + colh;
    auto* la = (__attribute__((address_space(3))) void*)(sA + chunk * 512 + lane * 8);
    __builtin_amdgcn_global_load_lds(
        (const __attribute__((address_space(1))) void*)(gA + grow), la, 16, 0, 0);
    auto* lb = (__attribute__((address_space(3))) void*)(sB + chunk * 512 + lane * 8);
    __builtin_amdgcn_global_load_lds(
        (const __attribute__((address_space(1))) void*)(gB + grow), lb, 16, 0, 0);
  }
}

__device__ __forceinline__ int lds_off(int row, int slot) {
  return row * 64 + ((slot ^ (row & 7)) * 8);
}

__global__ __launch_bounds__(256) void gemm_z(const _Float16* __restrict__ Xh,
                                              const _Float16* __restrict__ Wt,
                                              float* __restrict__ part, int B) {
  __shared__ _Float16 smA[2][128 * 64];
  __shared__ _Float16 smB[2][128 * 64];

  const int tid = threadIdx.x;
  const int lane = tid & 63;
  const int wv = tid >> 6;
  const int wm = wv >> 1, wn = wv & 1;
  const int row0 = blockIdx.x * 128;
  const int n0 = blockIdx.y * 128;

  const _Float16* gA = Xh + (size_t)row0 * 1024;
  const _Float16* gB = Wt + (size_t)n0 * 1024;

  const int lr = lane & 15;
  const int lq = lane >> 4;       // 0..3: which 8-f16 K-slot within 32

  f32x4v acc[4][4];
  #pragma unroll
  for (int m = 0; m < 4; ++m)
    #pragma unroll
    for (int f = 0; f < 4; ++f) acc[m][f] = f32x4v{0.f, 0.f, 0.f, 0.f};

  stage_tiles(gA, gB, smA[0], smB[0], 0, wv, lane);
  __syncthreads();

  for (int t = 0; t < GZ_NSTEP; ++t) {
    const int cur = t & 1;
    if (t + 1 < GZ_NSTEP)
      stage_tiles(gA, gB, smA[cur ^ 1], smB[cur ^ 1], (t + 1) * 64, wv, lane);

    #pragma unroll
    for (int kk = 0; kk < 2; ++kk) {
      const int slot = kk * 4 + lq;
      f16x8 a[4], b[4];
      #pragma unroll
      for (int m = 0; m < 4; ++m) {
        const int row = wm * 64 + m * 16 + lr;
        a[m] = *reinterpret_cast<const f16x8*>(&smA[cur][lds_off(row, slot)]);
      }
      #pragma unroll
      for (int f = 0; f < 4; ++f) {
        const int row = wn * 64 + f * 16 + lr;
        b[f] = *reinterpret_cast<const f16x8*>(&smB[cur][lds_off(row, slot)]);
      }
      #pragma unroll
      for (int m = 0; m < 4; ++m)
        #pragma unroll
        for (int f = 0; f < 4; ++f)
          acc[m][f] = __builtin_amdgcn_mfma_f32_16x16x32_f16(a[m], b[f], acc[m][f], 0, 0, 0);
    }
    __syncthreads();
  }

  // Epilogue: sum of squares over the wave's 64 N-rows (= 32 js re/im pairs).
  const int pp = blockIdx.y * 2 + wn;
  #pragma unroll
  for (int m = 0; m < 4; ++m) {
    f32x4v p = f32x4v{0.f, 0.f, 0.f, 0.f};
    #pragma unroll
    for (int f = 0; f < 4; ++f) p += acc[m][f] * acc[m][f];
    #pragma unroll
    for (int msk = 1; msk < 16; msk <<= 1) {
      p.x += __shfl_xor(p.x, msk, 64);
      p.y += __shfl_xor(p.y, msk, 64);
      p.z += __shfl_xor(p.z, msk, 64);
      p.w += __shfl_xor(p.w, msk, 64);
    }
    if (lr == 0) {
      const int rbase = row0 + wm * 64 + m * 16 + lq * 4;
      float* dst = part + (size_t)pp * B + rbase;
      dst[0] = p.x; dst[1] = p.y; dst[2] = p.z; dst[3] = p.w;
    }
  }
}

// logits from 32 chunk partials: sign0 = bit9 -> pp&16, sign1 = bit8 -> pp&8.
__global__ __launch_bounds__(1024) void nll_mean(const float* __restrict__ part,
                                                 const int* __restrict__ y,
                                                 float* __restrict__ out, int B) {
  const int t = threadIdx.x;
  const int rpt = B / 1024;
  float s = 0.f;
  for (int rr = 0; rr < rpt; ++rr) {
    const int row = t + rr * 1024;
    float q0 = 0.f, q1 = 0.f, nn = 0.f;
    #pragma unroll
    for (int pp = 0; pp < 32; ++pp) {
      const float P = part[(size_t)pp * B + row];
      q0 += (pp & 16) ? -P : P;
      q1 += (pp & 8) ? -P : P;
      nn += P;
    }
    const float z0 = q0 / nn, z1 = q1 / nn;
    const float mx = fmaxf(z0, z1);
    const float lse = mx + logf(expf(z0 - mx) + expf(z1 - mx));
    const float ly = (y[row] == 0) ? z0 : z1;
    s += lse - ly;
  }
  #pragma unroll
  for (int msk = 1; msk < 64; msk <<= 1) s += __shfl_xor(s, msk, 64);
  __shared__ float red[16];
  if ((t & 63) == 0) red[t >> 6] = s;
  __syncthreads();
  if (t == 0) {
    float tot = 0.f;
    #pragma unroll
    for (int q = 0; q < 16; ++q) tot += red[q];
    out[0] = tot / (float)B;
  }
}

} // namespace

extern "C" void kernel_launch(void* const* d_in, const int* in_sizes, int n_in,
                              void* d_out, int out_size, void* d_ws, size_t ws_size,
                              hipStream_t stream) {
  const float* x  = (const float*)d_in[0];
  const int*   y  = (const int*)d_in[1];
  const float* w  = (const float*)d_in[2];
  const float* w1 = (const float*)d_in[3];
  const float* w2 = (const float*)d_in[4];
  float* out = (float*)d_out;

  const int B = in_sizes[0] / 784;      // 8192

  char* ws = (char*)d_ws;
  _Float16* Wt   = (_Float16*)ws;                                // 4 MB
  _Float16* Xh   = (_Float16*)(ws + (size_t)2048 * 1024 * 2);    // 16 MB
  float*    part = (float*)(ws + (size_t)2048 * 1024 * 2 + (size_t)B * 1024 * 2);

  qprep<<<1024 + (B * 128) / 512, 512, 0, stream>>>(w, w1, w2, x, Wt, Xh);
  gemm_z<<<dim3(B / 128, 16), 256, 0, stream>>>(Xh, Wt, part, B);
  nll_mean<<<1, 1024, 0, stream>>>(part, y, out, B);
}

// Round 11
// 87.886 us; speedup vs baseline: 1.2658x; 1.2658x over previous
//
#include <hip/hip_runtime.h>

// CCQC classifier, GEMM formulation. R11: revert qprep to R9 4-wave (R10's
// 8-wave split regressed: 31 full-block barriers beat the occupancy gain);
// gemm_z to 8 waves/block (16 waves/CU); nll split into parallel partial+final.
//   1. qprep (blocks 0..1023): build rows of U via REVERSED ADJOINT circuit.
//      256-thread block per basis state; j = (wv<<8)|(k<<6)|lane, 4 f32x2
//      regs/lane. 101-gate pre-adjointed program computed into LDS at start.
//      Cross-wave gates (j-bits 8,9) via double-buffered exchange, 1 barrier.
//      Wt interleaved: row 2j=Re, 2j+1=Im.
//      Blocks >=1024: xconv X fp32 -> fp16 (overlaps build).
//   2. gemm_z: C = Xh * Wt^T, M=8192 N=2048 K=832, 128x128 tile, BK=64,
//      512 threads = 8 waves (4M x 2N, 32x64 each), double-buffered
//      global_load_lds, XOR bank-swizzle (both-sides), fused |psi|^2
//      epilogue -> 32 sign-uniform chunk partials.
//   3. nll_part (32 blocks) + nll_final: log-softmax NLL, mean.

namespace {

typedef float f32x2 __attribute__((ext_vector_type(2)));
typedef _Float16 f16x8 __attribute__((ext_vector_type(8)));
typedef float f32x4v __attribute__((ext_vector_type(4)));

__device__ __forceinline__ f32x2 swap2(f32x2 v) {
  return __builtin_shufflevector(v, v, 1, 0);
}
__device__ __forceinline__ f32x2 shfl_xor2(f32x2 v, int lm) {
  f32x2 r;
  r.x = __shfl_xor(v.x, lm, 64);
  r.y = __shfl_xor(v.y, lm, 64);
  return r;
}
__device__ __forceinline__ f32x2 sel2(bool c, f32x2 a, f32x2 b) {
  f32x2 r; r.x = c ? a.x : b.x; r.y = c ? a.y : b.y; return r;
}

struct c2 { float r, i; };
struct m2c { c2 a00, a01, a10, a11; };

__device__ __forceinline__ c2 cmul(c2 x, c2 y) { return {x.r*y.r - x.i*y.i, x.r*y.i + x.i*y.r}; }
__device__ __forceinline__ c2 cadd(c2 x, c2 y) { return {x.r + y.r, x.i + y.i}; }
__device__ __forceinline__ c2 conjc(c2 a) { return {a.r, -a.i}; }
__device__ __forceinline__ m2c mmul(m2c A, m2c B) {
  m2c C;
  C.a00 = cadd(cmul(A.a00, B.a00), cmul(A.a01, B.a10));
  C.a01 = cadd(cmul(A.a00, B.a01), cmul(A.a01, B.a11));
  C.a10 = cadd(cmul(A.a10, B.a00), cmul(A.a11, B.a10));
  C.a11 = cadd(cmul(A.a10, B.a01), cmul(A.a11, B.a11));
  return C;
}
__device__ __forceinline__ m2c mrx(float t) {
  float c = cosf(0.5f * t), s = sinf(0.5f * t);
  return { {c, 0.f}, {0.f, -s}, {0.f, -s}, {c, 0.f} };
}
__device__ __forceinline__ m2c mrz(float t) {
  float c = cosf(0.5f * t), s = sinf(0.5f * t);
  return { {c, -s}, {0.f, 0.f}, {0.f, 0.f}, {c, s} };
}

struct MatP { f32x2 u00r, u00i, u01r, u01i, u10r, u10i, u11r, u11i; };

__device__ __forceinline__ MatP ldmatL(const float* progL, int slot) {
  const float4* p = reinterpret_cast<const float4*>(progL + slot * 16);
  float4 a = p[0], b = p[1], c = p[2], d = p[3];
  MatP m;
  m.u00r = f32x2{a.x, a.y}; m.u00i = f32x2{a.z, a.w};
  m.u01r = f32x2{b.x, b.y}; m.u01i = f32x2{b.z, b.w};
  m.u10r = f32x2{c.x, c.y}; m.u10i = f32x2{c.z, c.w};
  m.u11r = f32x2{d.x, d.y}; m.u11i = f32x2{d.z, d.w};
  return m;
}

__device__ __forceinline__ f32x2 cmad(f32x2 acc, f32x2 cr2, f32x2 ci2, f32x2 v) {
  return acc + cr2 * v + ci2 * swap2(v);
}
__device__ __forceinline__ f32x2 cmulp(f32x2 cr2, f32x2 ci2, f32x2 v) {
  return cr2 * v + ci2 * swap2(v);
}

// ---- 4-reg (4 waves/state) gate appliers ----
__device__ __forceinline__ void g_xlane(f32x2 (&s)[4], const int lm,
                                        const f32x2 cAr, const f32x2 cAi,
                                        const f32x2 cBr, const f32x2 cBi,
                                        const int cm_reg) {
  #pragma unroll
  for (int k = 0; k < 4; ++k) {
    if (cm_reg && !(k & cm_reg)) continue;
    const f32x2 p = shfl_xor2(s[k], lm);
    s[k] = cmad(cmulp(cAr, cAi, s[k]), cBr, cBi, p);
  }
}
__device__ __forceinline__ void g_local(f32x2 (&s)[4], const int kb, const MatP m,
                                        const int cm_reg) {
  const int tm = 1 << kb;
  #pragma unroll
  for (int k0 = 0; k0 < 4; ++k0) {
    if (k0 & tm) continue;
    if (cm_reg && !(k0 & cm_reg)) continue;
    const int k1 = k0 | tm;
    const f32x2 a = s[k0], b = s[k1];
    s[k0] = cmad(cmulp(m.u00r, m.u00i, a), m.u01r, m.u01i, b);
    s[k1] = cmad(cmulp(m.u10r, m.u10i, a), m.u11r, m.u11i, b);
  }
}
// Single barrier per exchange: caller alternates lxb between two buffers.
__device__ __forceinline__ void g_xwave(f32x2 (&s)[4], f32x2* lxb, const int wv,
                                        const int lane, const int tb,
                                        const f32x2 cAr, const f32x2 cAi,
                                        const f32x2 cBr, const f32x2 cBi,
                                        const int cm_reg) {
  #pragma unroll
  for (int k = 0; k < 4; ++k) lxb[(wv * 4 + k) * 64 + lane] = s[k];
  __syncthreads();
  const int pw = wv ^ (1 << tb);
  #pragma unroll
  for (int k = 0; k < 4; ++k) {
    if (cm_reg && !(k & cm_reg)) continue;
    const f32x2 p = lxb[(pw * 4 + k) * 64 + lane];
    s[k] = cmad(cmulp(cAr, cAi, s[k]), cBr, cBi, p);
  }
}

__device__ __forceinline__ void apply_gate(f32x2 (&s)[4], f32x2* lxb, const int wv,
                                           const int lane, const MatP mIn,
                                           const int bt, const int bc) {
  MatP m = mIn;
  const f32x2 oner{1.f, 1.f}, zero{0.f, 0.f};
  int cm_reg = 0;
  bool fold = false, cl = true;
  if (bc >= 8)      { cl = ((wv >> (bc - 8)) & 1) != 0; fold = true; }
  else if (bc >= 6) { cm_reg = 1 << (bc - 6); }
  else if (bc >= 0) { cl = ((lane >> bc) & 1) != 0; fold = true; }

  if (bt >= 8) {
    const int tb = bt - 8;
    const bool hi = ((wv >> tb) & 1) != 0;
    f32x2 cAr = sel2(hi, m.u11r, m.u00r), cAi = sel2(hi, m.u11i, m.u00i);
    f32x2 cBr = sel2(hi, m.u10r, m.u01r), cBi = sel2(hi, m.u10i, m.u01i);
    if (fold) {
      cAr = sel2(cl, cAr, oner); cAi = sel2(cl, cAi, zero);
      cBr = sel2(cl, cBr, zero); cBi = sel2(cl, cBi, zero);
    }
    g_xwave(s, lxb, wv, lane, tb, cAr, cAi, cBr, cBi, cm_reg);
  } else if (bt >= 6) {
    if (fold) {
      m.u00r = sel2(cl, m.u00r, oner); m.u00i = sel2(cl, m.u00i, zero);
      m.u01r = sel2(cl, m.u01r, zero); m.u01i = sel2(cl, m.u01i, zero);
      m.u10r = sel2(cl, m.u10r, zero); m.u10i = sel2(cl, m.u10i, zero);
      m.u11r = sel2(cl, m.u11r, oner); m.u11i = sel2(cl, m.u11i, zero);
    }
    g_local(s, bt - 6, m, cm_reg);
  } else {
    const bool hi = ((lane >> bt) & 1) != 0;
    f32x2 cAr = sel2(hi, m.u11r, m.u00r), cAi = sel2(hi, m.u11i, m.u00i);
    f32x2 cBr = sel2(hi, m.u10r, m.u01r), cBi = sel2(hi, m.u10i, m.u01i);
    if (fold) {
      cAr = sel2(cl, cAr, oner); cAi = sel2(cl, cAi, zero);
      cBr = sel2(cl, cBr, zero); cBi = sel2(cl, cBi, zero);
    }
    g_xlane(s, 1 << bt, cAr, cAi, cBr, cBi, cm_reg);
  }
}

// Fused prep. Blocks <1024: build row n=blockIdx of U (4 waves, 4 regs/lane).
// Blocks >=1024: xconv. Program slot layout (reversed-adjoint exec order):
//   dd=0 (d=4): slot0 = U0; 1..10 = CU i=9..0; 11..20 = U1 i=9..0.
//   dd>=1: base=21+(dd-1)*20: 0..9 = CU i=9..0; 10..19 = U1 i=9..0.
// U0[d<4] pre-fused into U1[d+1, i=0]. 101 slots.
__global__ __launch_bounds__(256) void qprep(const float* __restrict__ w,
                                             const float* __restrict__ w1,
                                             const float* __restrict__ w2,
                                             const float* __restrict__ x,
                                             _Float16* __restrict__ Wt,
                                             _Float16* __restrict__ Xh) {
  const int tid = threadIdx.x;
  if (blockIdx.x >= 1024) {
    // ---- xconv ----
    const int t = (blockIdx.x - 1024) * 256 + tid;
    const int b = t >> 7;
    const int j = (t & 127) * 8;
    f16x8 o;
    if (j < 784) {
      const float4* p = reinterpret_cast<const float4*>(x + (size_t)b * 784 + j);
      const float4 v0 = p[0], v1 = p[1];
      o[0] = (_Float16)v0.x; o[1] = (_Float16)v0.y;
      o[2] = (_Float16)v0.z; o[3] = (_Float16)v0.w;
      o[4] = (_Float16)v1.x; o[5] = (_Float16)v1.y;
      o[6] = (_Float16)v1.z; o[7] = (_Float16)v1.w;
    } else {
      #pragma unroll
      for (int q = 0; q < 8; ++q) o[q] = (_Float16)0.f;
    }
    *reinterpret_cast<f16x8*>(Xh + (size_t)b * 1024 + j) = o;
    return;
  }

  // ---- build_W ----
  __shared__ float progL[101 * 16];
  __shared__ f32x2 lx[2][1024];   // double-buffered exchange

  if (tid < 105) {
    const int t = tid;
    m2c U{}; int slot = -1;
    if (t < 50) {
      const int d = t / 10, i = t % 10;
      const float* p = w + (d * 10 + i) * 5;
      U = mmul(mrx(p[2]), mmul(mrz(p[1]), mrx(p[0])));
      if (i == 0 && d > 0) {
        m2c U0 = mmul(mrz(w2[d - 1]), mrx(w1[d - 1]));
        U = mmul(U, U0);
      }
      const int dd = 4 - d;
      const int base = (dd == 0) ? 0 : 21 + (dd - 1) * 20;
      slot = base + ((d == 4) ? 11 : 10) + (9 - i);
    } else if (t < 100) {
      const int s = t - 50; const int d = s / 10, i = s % 10;
      const float* p = w + (d * 10 + i) * 5;
      U = mmul(mrx(p[4]), mrz(p[3]));
      const int dd = 4 - d;
      const int base = (dd == 0) ? 0 : 21 + (dd - 1) * 20;
      slot = base + ((d == 4) ? 1 : 0) + (9 - i);
    } else {
      const int d = t - 100;
      if (d == 4) {
        U = mmul(mrz(w2[d]), mrx(w1[d]));
        slot = 0;
      }
    }
    if (slot >= 0) {
      const c2 A[4] = {conjc(U.a00), conjc(U.a10), conjc(U.a01), conjc(U.a11)};
      float* o = progL + slot * 16;
      #pragma unroll
      for (int q = 0; q < 4; ++q) {
        o[q*4 + 0] = A[q].r; o[q*4 + 1] = A[q].r;
        o[q*4 + 2] = -A[q].i; o[q*4 + 3] = A[q].i;
      }
    }
  }
  __syncthreads();

  const int lane = tid & 63;
  const int wv = tid >> 6;
  const int n = blockIdx.x;

  f32x2 s[4];
  #pragma unroll
  for (int k = 0; k < 4; ++k) {
    const int j = (wv << 8) | (k << 6) | lane;
    s[k].x = (j == n) ? 1.f : 0.f;
    s[k].y = 0.f;
  }

  int p = 0, ph = 0;
  #pragma unroll
  for (int dd = 0; dd < 5; ++dd) {
    const int d = 4 - dd;
    if (d == 4) {
      apply_gate(s, &lx[ph & 1][0], wv, lane, ldmatL(progL, p), 9, -1);
      ++p; ++ph;
    }
    const int r = (d & 1) ? 3 : 1;
    #pragma unroll
    for (int ii = 0; ii < 10; ++ii) {
      const int i = 9 - ii;
      const int c = (i + r) % 10;
      const int bt = 9 - i, bc = 9 - c;
      apply_gate(s, &lx[ph & 1][0], wv, lane, ldmatL(progL, p), bt, bc);
      ++p; if (bt >= 8) ++ph;
    }
    #pragma unroll
    for (int ii = 0; ii < 10; ++ii) {
      const int i = 9 - ii;
      const int bt = 9 - i;
      apply_gate(s, &lx[ph & 1][0], wv, lane, ldmatL(progL, p), bt, -1);
      ++p; if (bt >= 8) ++ph;
    }
  }

  // psi = U^dagger e_n => U[n][j] = (s.x, -s.y)
  #pragma unroll
  for (int k = 0; k < 4; ++k) {
    const int j = (wv << 8) | (k << 6) | lane;
    Wt[(size_t)(2 * n) * 1024 + j] = (_Float16)s[k].x;
    Wt[(size_t)(2 * n + 1) * 1024 + j] = (_Float16)(-s[k].y);
  }
}

// ---------------- LDS-staged GEMM ----------------
// Tile 128(M) x 128(N-rows, interleaved re/im = 64 js), BK=64, 13 K-steps.
// R11: 512 threads = 8 waves (4M x 2N), wave tile 32x64 -> 16 waves/CU.
// LDS swizzle: row r's 8 16B-slots permuted s -> s^(r&7); staged with linear
// LDS dest + swizzled GLOBAL source; read with same XOR (rule #21).
#define GZ_NSTEP 13

__device__ __forceinline__ void stage_tiles(const _Float16* __restrict__ gA,
                                            const _Float16* __restrict__ gB,
                                            _Float16* sA, _Float16* sB,
                                            int k0, int wv, int lane) {
  const int rIn = lane >> 3;                    // row within chunk (0..7)
  const int colh = ((lane & 7) ^ rIn) * 8;      // swizzled source 16B-slot
  #pragma unroll
  for (int c = 0; c < 2; ++c) {
    const int chunk = wv * 2 + c;
    const size_t grow = (size_t)(chunk * 8 + rIn) * 1024 + k0 + colh;
    auto* la = (__attribute__((address_space(3))) void*)(sA + chunk * 512 + lane * 8);
    __builtin_amdgcn_global_load_lds(
        (const __attribute__((address_space(1))) void*)(gA + grow), la, 16, 0, 0);
    auto* lb = (__attribute__((address_space(3))) void*)(sB + chunk * 512 + lane * 8);
    __builtin_amdgcn_global_load_lds(
        (const __attribute__((address_space(1))) void*)(gB + grow), lb, 16, 0, 0);
  }
}

__device__ __forceinline__ int lds_off(int row, int slot) {
  return row * 64 + ((slot ^ (row & 7)) * 8);
}

__global__ __launch_bounds__(512) void gemm_z(const _Float16* __restrict__ Xh,
                                              const _Float16* __restrict__ Wt,
                                              float* __restrict__ part, int B) {
  __shared__ _Float16 smA[2][128 * 64];
  __shared__ _Float16 smB[2][128 * 64];

  const int tid = threadIdx.x;
  const int lane = tid & 63;
  const int wv = tid >> 6;        // 0..7
  const int wm = wv >> 1;         // 0..3 (M)
  const int wn = wv & 1;          // 0..1 (N)
  const int row0 = blockIdx.x * 128;
  const int n0 = blockIdx.y * 128;

  const _Float16* gA = Xh + (size_t)row0 * 1024;
  const _Float16* gB = Wt + (size_t)n0 * 1024;

  const int lr = lane & 15;
  const int lq = lane >> 4;       // 0..3: which 8-f16 K-slot within 32

  f32x4v acc[2][4];
  #pragma unroll
  for (int m = 0; m < 2; ++m)
    #pragma unroll
    for (int f = 0; f < 4; ++f) acc[m][f] = f32x4v{0.f, 0.f, 0.f, 0.f};

  stage_tiles(gA, gB, smA[0], smB[0], 0, wv, lane);
  __syncthreads();

  for (int t = 0; t < GZ_NSTEP; ++t) {
    const int cur = t & 1;
    if (t + 1 < GZ_NSTEP)
      stage_tiles(gA, gB, smA[cur ^ 1], smB[cur ^ 1], (t + 1) * 64, wv, lane);

    #pragma unroll
    for (int kk = 0; kk < 2; ++kk) {
      const int slot = kk * 4 + lq;
      f16x8 a[2], b[4];
      #pragma unroll
      for (int m = 0; m < 2; ++m) {
        const int row = wm * 32 + m * 16 + lr;
        a[m] = *reinterpret_cast<const f16x8*>(&smA[cur][lds_off(row, slot)]);
      }
      #pragma unroll
      for (int f = 0; f < 4; ++f) {
        const int row = wn * 64 + f * 16 + lr;
        b[f] = *reinterpret_cast<const f16x8*>(&smB[cur][lds_off(row, slot)]);
      }
      #pragma unroll
      for (int m = 0; m < 2; ++m)
        #pragma unroll
        for (int f = 0; f < 4; ++f)
          acc[m][f] = __builtin_amdgcn_mfma_f32_16x16x32_f16(a[m], b[f], acc[m][f], 0, 0, 0);
    }
    __syncthreads();
  }

  // Epilogue: sum of squares over the wave's 64 N-rows (= 32 js re/im pairs).
  const int pp = blockIdx.y * 2 + wn;
  #pragma unroll
  for (int m = 0; m < 2; ++m) {
    f32x4v p = f32x4v{0.f, 0.f, 0.f, 0.f};
    #pragma unroll
    for (int f = 0; f < 4; ++f) p += acc[m][f] * acc[m][f];
    #pragma unroll
    for (int msk = 1; msk < 16; msk <<= 1) {
      p.x += __shfl_xor(p.x, msk, 64);
      p.y += __shfl_xor(p.y, msk, 64);
      p.z += __shfl_xor(p.z, msk, 64);
      p.w += __shfl_xor(p.w, msk, 64);
    }
    if (lr == 0) {
      const int rbase = row0 + wm * 32 + m * 16 + lq * 4;
      float* dst = part + (size_t)pp * B + rbase;
      dst[0] = p.x; dst[1] = p.y; dst[2] = p.z; dst[3] = p.w;
    }
  }
}

// ---- NLL: 32-block partial + final reduce (deterministic) ----
__global__ __launch_bounds__(256) void nll_part(const float* __restrict__ part,
                                                const int* __restrict__ y,
                                                float* __restrict__ out2, int B) {
  const int row = blockIdx.x * 256 + threadIdx.x;
  float q0 = 0.f, q1 = 0.f, nn = 0.f;
  #pragma unroll
  for (int pp = 0; pp < 32; ++pp) {
    const float P = part[(size_t)pp * B + row];
    q0 += (pp & 16) ? -P : P;
    q1 += (pp & 8) ? -P : P;
    nn += P;
  }
  const float z0 = q0 / nn, z1 = q1 / nn;
  const float mx = fmaxf(z0, z1);
  const float lse = mx + logf(expf(z0 - mx) + expf(z1 - mx));
  const float ly = (y[row] == 0) ? z0 : z1;
  float s = lse - ly;
  #pragma unroll
  for (int msk = 1; msk < 64; msk <<= 1) s += __shfl_xor(s, msk, 64);
  __shared__ float red[4];
  if ((threadIdx.x & 63) == 0) red[threadIdx.x >> 6] = s;
  __syncthreads();
  if (threadIdx.x == 0) out2[blockIdx.x] = red[0] + red[1] + red[2] + red[3];
}

__global__ void nll_final(const float* __restrict__ out2, float* __restrict__ out,
                          int nblk, float scale) {
  const int t = threadIdx.x;
  float s = (t < nblk) ? out2[t] : 0.f;
  #pragma unroll
  for (int msk = 1; msk < 64; msk <<= 1) s += __shfl_xor(s, msk, 64);
  if (t == 0) out[0] = s * scale;
}

} // namespace

extern "C" void kernel_launch(void* const* d_in, const int* in_sizes, int n_in,
                              void* d_out, int out_size, void* d_ws, size_t ws_size,
                              hipStream_t stream) {
  const float* x  = (const float*)d_in[0];
  const int*   y  = (const int*)d_in[1];
  const float* w  = (const float*)d_in[2];
  const float* w1 = (const float*)d_in[3];
  const float* w2 = (const float*)d_in[4];
  float* out = (float*)d_out;

  const int B = in_sizes[0] / 784;      // 8192

  char* ws = (char*)d_ws;
  _Float16* Wt   = (_Float16*)ws;                                // 4 MB
  _Float16* Xh   = (_Float16*)(ws + (size_t)2048 * 1024 * 2);    // 16 MB
  float*    part = (float*)(ws + (size_t)2048 * 1024 * 2 + (size_t)B * 1024 * 2);
  float*    out2 = part + (size_t)32 * B;

  qprep<<<1024 + (B * 128) / 256, 256, 0, stream>>>(w, w1, w2, x, Wt, Xh);
  gemm_z<<<dim3(B / 128, 16), 512, 0, stream>>>(Xh, Wt, part, B);
  nll_part<<<B / 256, 256, 0, stream>>>(part, y, out2, B);
  nll_final<<<1, 64, 0, stream>>>(out2, out, B / 256, 1.0f / (float)B);
}